// Round 2
// baseline (206.701 us; speedup 1.0000x reference)
//
#include <hip/hip_runtime.h>
#include <hip/hip_cooperative_groups.h>

namespace cg = cooperative_groups;

// Reservoir sampling "add", fused single cooperative kernel:
//   Phase A: winner[s] = fill-phase winner (plain stores; covers all n slots,
//            so no memset and no dependence on d_ws contents)
//   grid.sync()
//   Phase B: random-phase samples (idx >= n) compute j via threefry2x32
//            (partitionable mode) and atomicMax their order into winner[j]
//   grid.sync()
//   Phase C: gather — out[s] = winner[s] >= 0 ? samples[winner[s]] : buffer[s]
//            16 rows/block in 2 chunks of 8 for load ILP.

#define D_FEAT 1024
#define GRID_BLOCKS 1024
#define BLOCK_THREADS 256

#define ROTL32(x, r) (((x) << (r)) | ((x) >> (32 - (r))))

__device__ __forceinline__ void tf2x32(unsigned k0, unsigned k1,
                                       unsigned x0, unsigned x1,
                                       unsigned& o0, unsigned& o1) {
  const unsigned ks2 = k0 ^ k1 ^ 0x1BD11BDAu;
  x0 += k0; x1 += k1;
  x0 += x1; x1 = ROTL32(x1, 13); x1 ^= x0;
  x0 += x1; x1 = ROTL32(x1, 15); x1 ^= x0;
  x0 += x1; x1 = ROTL32(x1, 26); x1 ^= x0;
  x0 += x1; x1 = ROTL32(x1, 6);  x1 ^= x0;
  x0 += k1; x1 += ks2 + 1u;
  x0 += x1; x1 = ROTL32(x1, 17); x1 ^= x0;
  x0 += x1; x1 = ROTL32(x1, 29); x1 ^= x0;
  x0 += x1; x1 = ROTL32(x1, 16); x1 ^= x0;
  x0 += x1; x1 = ROTL32(x1, 24); x1 ^= x0;
  x0 += ks2; x1 += k0 + 2u;
  x0 += x1; x1 = ROTL32(x1, 13); x1 ^= x0;
  x0 += x1; x1 = ROTL32(x1, 15); x1 ^= x0;
  x0 += x1; x1 = ROTL32(x1, 26); x1 ^= x0;
  x0 += x1; x1 = ROTL32(x1, 6);  x1 ^= x0;
  x0 += k0; x1 += k1 + 3u;
  x0 += x1; x1 = ROTL32(x1, 17); x1 ^= x0;
  x0 += x1; x1 = ROTL32(x1, 29); x1 ^= x0;
  x0 += x1; x1 = ROTL32(x1, 16); x1 ^= x0;
  x0 += x1; x1 = ROTL32(x1, 24); x1 ^= x0;
  x0 += k1; x1 += ks2 + 4u;
  x0 += x1; x1 = ROTL32(x1, 13); x1 ^= x0;
  x0 += x1; x1 = ROTL32(x1, 15); x1 ^= x0;
  x0 += x1; x1 = ROTL32(x1, 26); x1 ^= x0;
  x0 += x1; x1 = ROTL32(x1, 6);  x1 ^= x0;
  x0 += ks2; x1 += k0 + 5u;
  o0 = x0; o1 = x1;
}

__global__ __launch_bounds__(BLOCK_THREADS, 4)
void reservoir_fused(const int* __restrict__ i0p,
                     const float4* __restrict__ buf,
                     const float4* __restrict__ smp,
                     int* __restrict__ winner,
                     float4* __restrict__ out,
                     int N, int n) {
  const int tid = blockIdx.x * blockDim.x + threadIdx.x;
  const int nthreads = gridDim.x * blockDim.x;
  const int i0 = i0p[0];

  // ---- Phase A: fill-phase winners (covers every slot; no memset needed)
  for (int s = tid; s < n; s += nthreads) {
    int k = s - i0;                       // fill sample order targeting slot s
    winner[s] = (k >= 0 && k < N) ? k : -1;
  }

  cg::this_grid().sync();

  // ---- Phase B: random-phase samples
  for (int k = tid; k < N; k += nthreads) {
    const int idx = i0 + k;
    if (idx < n) continue;                // fill phase handled above
    unsigned k1a, k1b, k2a, k2b;
    tf2x32(0u, 42u, 0u, 0u, k1a, k1b);    // split subkeys of key(42) — const-folded
    tf2x32(0u, 42u, 0u, 1u, k2a, k2b);
    unsigned b1, b2;
    tf2x32(k1a, k1b, 0u, (unsigned)k, b1, b2);
    const unsigned hb = b1 ^ b2;
    tf2x32(k2a, k2b, 0u, (unsigned)k, b1, b2);
    const unsigned lb = b1 ^ b2;
    const unsigned span = (unsigned)(idx + 1);
    unsigned mult = 65536u % span;
    mult = (mult * mult) % span;
    const unsigned j = ((hb % span) * mult + (lb % span)) % span;
    if (j < (unsigned)n) atomicMax(&winner[j], k);
  }

  cg::this_grid().sync();

  // ---- Phase C: gather, 16 rows/block in 2 chunks of 8 (load ILP)
  const int D4 = D_FEAT / 4;              // 256 float4 per row
  const int t = threadIdx.x;
  for (int rbase = blockIdx.x; rbase < n; rbase += 8 * gridDim.x) {
    const float4* src[8];
    int rr[8];
    int nr = 0;
    #pragma unroll
    for (int j = 0; j < 8; ++j) {
      int r = rbase + j * gridDim.x;
      if (r < n) {
        int w = winner[r];
        src[nr] = (w >= 0) ? (smp + (size_t)w * D4) : (buf + (size_t)r * D4);
        rr[nr] = r;
        ++nr;
      }
    }
    float4 v[8];
    #pragma unroll
    for (int j = 0; j < 8; ++j)
      if (j < nr) v[j] = src[j][t];
    #pragma unroll
    for (int j = 0; j < 8; ++j)
      if (j < nr) out[(size_t)rr[j] * D4 + t] = v[j];
  }
}

extern "C" void kernel_launch(void* const* d_in, const int* in_sizes, int n_in,
                              void* d_out, int out_size, void* d_ws, size_t ws_size,
                              hipStream_t stream) {
  const float4* buffer  = (const float4*)d_in[0];
  const float4* samples = (const float4*)d_in[1];
  const int*    i0p     = (const int*)d_in[2];
  float4* out = (float4*)d_out;

  int n = out_size / D_FEAT;              // 16384 reservoir slots
  int N = in_sizes[1] / D_FEAT;           // 65536 incoming samples
  int* winner = (int*)d_ws;

  void* args[] = {(void*)&i0p, (void*)&buffer, (void*)&samples,
                  (void*)&winner, (void*)&out, (void*)&N, (void*)&n};
  hipLaunchCooperativeKernel((const void*)reservoir_fused,
                             dim3(GRID_BLOCKS), dim3(BLOCK_THREADS),
                             args, 0, stream);
}

// Round 3
// 33.411 us; speedup vs baseline: 6.1866x; 6.1866x over previous
//
#include <hip/hip_runtime.h>

// Reservoir sampling "add" — 3 dispatches:
//   K1 init_winner: winner[s] = fill-phase winner (s-i0 if in [0,N)) else -1.
//   K2 random_winner: samples with idx >= n draw j via threefry2x32
//      (partitionable mode, matches modern JAX) and atomicMax order k
//      into winner[j] when j < n.
//   K3 gather8: out[s] = winner[s] >= 0 ? samples[winner[s]] : buffer[s].
//      8 rows per block, fully unrolled (static indices only — rule #20),
//      4 independent 16B loads in flight per thread.

#define D_FEAT 1024
#define D4 256            // float4 per row
#define ROWS_PER_BLOCK 8

#define ROTL32(x, r) (((x) << (r)) | ((x) >> (32 - (r))))

__device__ __forceinline__ void tf2x32(unsigned k0, unsigned k1,
                                       unsigned x0, unsigned x1,
                                       unsigned& o0, unsigned& o1) {
  const unsigned ks2 = k0 ^ k1 ^ 0x1BD11BDAu;
  x0 += k0; x1 += k1;
  x0 += x1; x1 = ROTL32(x1, 13); x1 ^= x0;
  x0 += x1; x1 = ROTL32(x1, 15); x1 ^= x0;
  x0 += x1; x1 = ROTL32(x1, 26); x1 ^= x0;
  x0 += x1; x1 = ROTL32(x1, 6);  x1 ^= x0;
  x0 += k1; x1 += ks2 + 1u;
  x0 += x1; x1 = ROTL32(x1, 17); x1 ^= x0;
  x0 += x1; x1 = ROTL32(x1, 29); x1 ^= x0;
  x0 += x1; x1 = ROTL32(x1, 16); x1 ^= x0;
  x0 += x1; x1 = ROTL32(x1, 24); x1 ^= x0;
  x0 += ks2; x1 += k0 + 2u;
  x0 += x1; x1 = ROTL32(x1, 13); x1 ^= x0;
  x0 += x1; x1 = ROTL32(x1, 15); x1 ^= x0;
  x0 += x1; x1 = ROTL32(x1, 26); x1 ^= x0;
  x0 += x1; x1 = ROTL32(x1, 6);  x1 ^= x0;
  x0 += k0; x1 += k1 + 3u;
  x0 += x1; x1 = ROTL32(x1, 17); x1 ^= x0;
  x0 += x1; x1 = ROTL32(x1, 29); x1 ^= x0;
  x0 += x1; x1 = ROTL32(x1, 16); x1 ^= x0;
  x0 += x1; x1 = ROTL32(x1, 24); x1 ^= x0;
  x0 += k1; x1 += ks2 + 4u;
  x0 += x1; x1 = ROTL32(x1, 13); x1 ^= x0;
  x0 += x1; x1 = ROTL32(x1, 15); x1 ^= x0;
  x0 += x1; x1 = ROTL32(x1, 26); x1 ^= x0;
  x0 += x1; x1 = ROTL32(x1, 6);  x1 ^= x0;
  x0 += ks2; x1 += k0 + 5u;
  o0 = x0; o1 = x1;
}

__global__ __launch_bounds__(256)
void init_winner(const int* __restrict__ i0p, int* __restrict__ winner,
                 int N, int n) {
  const int s = blockIdx.x * blockDim.x + threadIdx.x;
  if (s >= n) return;
  const int k = s - i0p[0];   // fill-phase sample order targeting slot s
  winner[s] = (k >= 0 && k < N) ? k : -1;
}

__global__ __launch_bounds__(256)
void random_winner(const int* __restrict__ i0p, int* __restrict__ winner,
                   int N, int n) {
  const int k = blockIdx.x * blockDim.x + threadIdx.x;
  if (k >= N) return;
  const int idx = i0p[0] + k;
  if (idx < n) return;                    // fill phase handled by init_winner
  // split subkeys of jax.random.key(42) — constant args, const-folded
  unsigned k1a, k1b, k2a, k2b;
  tf2x32(0u, 42u, 0u, 0u, k1a, k1b);
  tf2x32(0u, 42u, 0u, 1u, k2a, k2b);
  unsigned b1, b2;
  tf2x32(k1a, k1b, 0u, (unsigned)k, b1, b2);
  const unsigned hb = b1 ^ b2;
  tf2x32(k2a, k2b, 0u, (unsigned)k, b1, b2);
  const unsigned lb = b1 ^ b2;
  const unsigned span = (unsigned)(idx + 1);
  unsigned mult = 65536u % span;
  mult = (mult * mult) % span;
  const unsigned j = ((hb % span) * mult + (lb % span)) % span;
  if (j < (unsigned)n) atomicMax(&winner[j], k);
}

__global__ __launch_bounds__(256)
void gather8(const float4* __restrict__ buf, const float4* __restrict__ smp,
             const int* __restrict__ winner, float4* __restrict__ out, int n) {
  const int t = threadIdx.x;                     // float4 column, 0..255
  const int r0 = blockIdx.x * ROWS_PER_BLOCK;

  if (r0 + ROWS_PER_BLOCK <= n) {
    // fast path: fully unrolled, all indices compile-time after unroll
    int w[ROWS_PER_BLOCK];
    #pragma unroll
    for (int j = 0; j < ROWS_PER_BLOCK; ++j) w[j] = winner[r0 + j];

    #pragma unroll
    for (int g = 0; g < ROWS_PER_BLOCK / 4; ++g) {
      float4 v[4];
      #pragma unroll
      for (int j = 0; j < 4; ++j) {
        const int r = r0 + g * 4 + j;
        const int wj = w[g * 4 + j];
        const float4* src = (wj >= 0) ? (smp + (size_t)wj * D4)
                                      : (buf + (size_t)r * D4);
        v[j] = src[t];
      }
      #pragma unroll
      for (int j = 0; j < 4; ++j)
        out[(size_t)(r0 + g * 4 + j) * D4 + t] = v[j];
    }
  } else {
    for (int r = r0; r < n; ++r) {
      const int wj = winner[r];
      const float4* src = (wj >= 0) ? (smp + (size_t)wj * D4)
                                    : (buf + (size_t)r * D4);
      out[(size_t)r * D4 + t] = src[t];
    }
  }
}

extern "C" void kernel_launch(void* const* d_in, const int* in_sizes, int n_in,
                              void* d_out, int out_size, void* d_ws, size_t ws_size,
                              hipStream_t stream) {
  const float4* buffer  = (const float4*)d_in[0];
  const float4* samples = (const float4*)d_in[1];
  const int*    i0p     = (const int*)d_in[2];
  float4* out = (float4*)d_out;

  const int n = out_size / D_FEAT;        // 16384 reservoir slots
  const int N = in_sizes[1] / D_FEAT;     // 65536 incoming samples
  int* winner = (int*)d_ws;

  init_winner<<<(n + 255) / 256, 256, 0, stream>>>(i0p, winner, N, n);
  random_winner<<<(N + 255) / 256, 256, 0, stream>>>(i0p, winner, N, n);

  const int nblk = (n + ROWS_PER_BLOCK - 1) / ROWS_PER_BLOCK;  // 2048
  gather8<<<nblk, 256, 0, stream>>>(buffer, samples, winner, out, n);
}